// Round 9
// baseline (937.715 us; speedup 1.0000x reference)
//
#include <hip/hip_runtime.h>

typedef unsigned short ushort_t;
typedef __attribute__((ext_vector_type(8))) short bf16x8;
typedef __attribute__((ext_vector_type(4))) float f32x4v;

#define EPB 8000   // edges per sort block
#define BKT 128    // targets per bucket (lt = 7 bits)

static __device__ __forceinline__ float bf2f(ushort_t u) {
  union { unsigned int i; float f; } v; v.i = ((unsigned int)u) << 16; return v.f;
}
static __device__ __forceinline__ ushort_t f2bf(float f) {
  union { float f; unsigned int i; } v; v.f = f;
  unsigned int r = v.i + 0x7FFFu + ((v.i >> 16) & 1u);
  return (ushort_t)(r >> 16);
}
static __device__ __forceinline__ float leaky(float s) {
  return s > 0.f ? s : 0.2f * s;
}

// ---------------------------------------------------------------------------
// FUSED: block nb3 packs W_ext into B-fragments; blocks 0..nb3-1 histogram
// edges into 128-target coarse buckets.
// ---------------------------------------------------------------------------
__global__ __launch_bounds__(256) void packw_hist(
    const float* __restrict__ W, const float* __restrict__ attnl,
    const float* __restrict__ attnr, ushort_t* __restrict__ wfrag,
    const int* __restrict__ trg, int E, int nbkt,
    int* __restrict__ blockHist, int nb3)
{
  const int b = blockIdx.x;
  const int t = threadIdx.x;
  if (b == nb3) {
    const int kc = t >> 6, l = t & 63;
    const int q = l >> 4, n = l & 15;
    #pragma unroll
    for (int tile = 0; tile < 5; ++tile) {
      #pragma unroll
      for (int j = 0; j < 8; ++j) {
        const int k = kc * 32 + q * 8 + j;
        float v = 0.f;
        if (tile < 4) {
          v = W[k * 64 + tile * 16 + n];
        } else if (n < 4) {
          for (int f = 0; f < 16; ++f)
            v += W[k * 64 + n * 16 + f] * attnl[n * 16 + f];
        } else if (n < 8) {
          const int hd = n - 4;
          for (int f = 0; f < 16; ++f)
            v += W[k * 64 + hd * 16 + f] * attnr[hd * 16 + f];
        }
        wfrag[((tile * 4 + kc) * 64 + l) * 8 + j] = f2bf(v);
      }
    }
    return;
  }
  __shared__ int hist[1024];
  #pragma unroll
  for (int i = 0; i < 4; ++i) hist[i * 256 + t] = 0;
  __syncthreads();
  const int start = b * EPB;
  const int end = min(start + EPB, E);
  for (int e = start + t; e < end; e += 256)
    atomicAdd(&hist[trg[e] >> 7], 1);
  __syncthreads();
  for (int i = t; i < nbkt; i += 256) blockHist[b * nbkt + i] = hist[i];
}

// ---------------------------------------------------------------------------
// Per-bucket column scan of blockHist -> in-place exclusive prefix + total.
// ---------------------------------------------------------------------------
__global__ __launch_bounds__(64) void bucket_scan(
    int* __restrict__ blockHist, int nb3, int nbkt, int* __restrict__ colTotal)
{
  const int b = blockIdx.x;
  const int l = threadIdx.x;
  int carry = 0;
  for (int r = 0; r * 64 < nb3; ++r) {
    const int i = r * 64 + l;
    int v = (i < nb3) ? blockHist[i * nbkt + b] : 0;
    int incl = v;
    #pragma unroll
    for (int d = 1; d < 64; d <<= 1) {
      int u = __shfl_up(incl, d, 64);
      if (l >= d) incl += u;
    }
    if (i < nb3) blockHist[i * nbkt + b] = carry + incl - v;
    carry += __shfl(incl, 63, 64);
  }
  if (l == 0) colTotal[b] = carry;
}

// ---------------------------------------------------------------------------
// Scan colTotal -> bucketBase; fused gmaxM reduce (softmax shift bound).
// ---------------------------------------------------------------------------
__global__ __launch_bounds__(256) void bucket_base(
    const int* __restrict__ colTotal, int nbkt, int* __restrict__ bucketBase,
    const float* __restrict__ blockmax2, int nbL, float* __restrict__ gmaxM)
{
  const int t = threadIdx.x;
  const int l = t & 63, w = t >> 6;
  if (w == 0) {
    int carry = 0;
    for (int r = 0; r * 64 < nbkt; ++r) {
      const int i = r * 64 + l;
      int v = (i < nbkt) ? colTotal[i] : 0;
      int incl = v;
      #pragma unroll
      for (int d = 1; d < 64; d <<= 1) {
        int u = __shfl_up(incl, d, 64);
        if (l >= d) incl += u;
      }
      if (i < nbkt) bucketBase[i] = carry + incl - v;
      carry += __shfl(incl, 63, 64);
    }
    if (l == 0) bucketBase[nbkt] = carry;
  }
  float mel = -1e30f, mer = -1e30f;
  for (int i = t; i < nbL; i += 256) {
    mel = fmaxf(mel, blockmax2[i * 2]);
    mer = fmaxf(mer, blockmax2[i * 2 + 1]);
  }
  #pragma unroll
  for (int o = 1; o <= 32; o <<= 1) {
    mel = fmaxf(mel, __shfl_xor(mel, o, 64));
    mer = fmaxf(mer, __shfl_xor(mer, o, 64));
  }
  __shared__ float wm[8];
  if (l == 0) { wm[w * 2] = mel; wm[w * 2 + 1] = mer; }
  __syncthreads();
  if (t == 0) {
    float aa = fmaxf(fmaxf(wm[0], wm[2]), fmaxf(wm[4], wm[6]));
    float cc = fmaxf(fmaxf(wm[1], wm[3]), fmaxf(wm[5], wm[7]));
    gmaxM[0] = fmaxf(0.f, aa + cc);
  }
}

// ---------------------------------------------------------------------------
// Deterministic coarse scatter (no global atomics); payload (src<<7)|localTrg.
// ---------------------------------------------------------------------------
__global__ __launch_bounds__(256) void bucket_scatter(
    const int* __restrict__ src, const int* __restrict__ trg, int E, int nbkt,
    const int* __restrict__ blockHist, const int* __restrict__ bucketBase,
    unsigned int* __restrict__ binned)
{
  __shared__ int cursor[1024];
  const int t = threadIdx.x, b = blockIdx.x;
  for (int i = t; i < nbkt; i += 256)
    cursor[i] = bucketBase[i] + blockHist[b * nbkt + i];
  __syncthreads();
  const int start = b * EPB;
  const int end = min(start + EPB, E);
  for (int e = start + t; e < end; e += 256) {
    const int ti = trg[e];
    const int bkt = ti >> 7;
    const int pos = atomicAdd(&cursor[bkt], 1);
    binned[pos] = ((unsigned int)src[e] << 7) | (unsigned int)(ti & 127);
  }
}

// ---------------------------------------------------------------------------
// Kernel A (MFMA): h_ext = feat @ W_ext (unchanged from round 8).
// ---------------------------------------------------------------------------
__global__ __launch_bounds__(256) void gat_linear(
    const float* __restrict__ feat, const ushort_t* __restrict__ wfrag,
    ushort_t* __restrict__ h_out, float* __restrict__ el, float* __restrict__ er,
    float* __restrict__ blockmax2, int N)
{
  __shared__ ushort_t sFb[64 * 136];
  __shared__ float wmax[8];
  const int t = threadIdx.x;
  const int b = blockIdx.x;
  const int w = t >> 6, l = t & 63;
  const int q = l >> 4, m = l & 15;

  const float4* gF = (const float4*)(feat + (size_t)b * 64 * 128);
  #pragma unroll
  for (int i = 0; i < 8; ++i) {
    const int idx = i * 256 + t;
    const int node = idx >> 5, off = idx & 31;
    float4 v = make_float4(0.f, 0.f, 0.f, 0.f);
    if (b * 64 + node < N) v = gF[idx];
    unsigned int p0 = ((unsigned int)f2bf(v.y) << 16) | f2bf(v.x);
    unsigned int p1 = ((unsigned int)f2bf(v.w) << 16) | f2bf(v.z);
    *(uint2*)(sFb + node * 136 + off * 4) = make_uint2(p0, p1);
  }
  __syncthreads();

  bf16x8 a[4];
  const ushort_t* arow = sFb + (w * 16 + m) * 136 + q * 8;
  #pragma unroll
  for (int kc = 0; kc < 4; ++kc)
    a[kc] = *(const bf16x8*)(arow + kc * 32);

  #pragma unroll
  for (int tile = 0; tile < 4; ++tile) {
    f32x4v acc = {0.f, 0.f, 0.f, 0.f};
    #pragma unroll
    for (int kc = 0; kc < 4; ++kc) {
      bf16x8 bfr = *(const bf16x8*)(wfrag + ((tile * 4 + kc) * 64 + l) * 8);
      acc = __builtin_amdgcn_mfma_f32_16x16x32_bf16(a[kc], bfr, acc, 0, 0, 0);
    }
    #pragma unroll
    for (int r = 0; r < 4; ++r) {
      const int gn = b * 64 + w * 16 + q * 4 + r;
      if (gn < N) h_out[(size_t)gn * 64 + tile * 16 + m] = f2bf(acc[r]);
    }
  }

  f32x4v acc4 = {0.f, 0.f, 0.f, 0.f};
  #pragma unroll
  for (int kc = 0; kc < 4; ++kc) {
    bf16x8 bfr = *(const bf16x8*)(wfrag + ((4 * 4 + kc) * 64 + l) * 8);
    acc4 = __builtin_amdgcn_mfma_f32_16x16x32_bf16(a[kc], bfr, acc4, 0, 0, 0);
  }
  float mel = -1e30f, mer = -1e30f;
  #pragma unroll
  for (int r = 0; r < 4; ++r) {
    const int gn = b * 64 + w * 16 + q * 4 + r;
    const float v = acc4[r];
    if (m < 4) {
      if (gn < N) el[gn * 4 + m] = v;
      mel = fmaxf(mel, v);
    } else if (m < 8) {
      if (gn < N) er[gn * 4 + (m - 4)] = v;
      mer = fmaxf(mer, v);
    }
  }
  #pragma unroll
  for (int o = 1; o <= 32; o <<= 1) {
    mel = fmaxf(mel, __shfl_xor(mel, o, 64));
    mer = fmaxf(mer, __shfl_xor(mer, o, 64));
  }
  if (l == 0) { wmax[w * 2] = mel; wmax[w * 2 + 1] = mer; }
  __syncthreads();
  if (t == 0) {
    float aa = fmaxf(fmaxf(wmax[0], wmax[2]), fmaxf(wmax[4], wmax[6]));
    float cc = fmaxf(fmaxf(wmax[1], wmax[3]), fmaxf(wmax[5], wmax[7]));
    blockmax2[b * 2] = aa;
    blockmax2[b * 2 + 1] = cc;
  }
}

// ---------------------------------------------------------------------------
// FUSED aggregation: one block per 128-target bucket. LDS accumulators
// (acc[128][64] = 32 KB), ds_add_f32 fire-and-forget (no dep chain).
// Epilogue: divide by dacc, coalesced float4 stores.
// ---------------------------------------------------------------------------
__global__ __launch_bounds__(256) void gat_fusedagg(
    const unsigned int* __restrict__ binned, const int* __restrict__ bucketBase,
    const float4* __restrict__ el4, const float4* __restrict__ er4,
    const ushort_t* __restrict__ hbf, const float* __restrict__ gmaxM,
    float* __restrict__ out, int N)
{
  __shared__ float acc[BKT * 64];   // 32 KB
  __shared__ float dacc[BKT * 4];   // 2 KB
  __shared__ float erl[BKT * 4];    // 2 KB
  __shared__ float sP[4 * 64 * 4];  // 4 KB
  const int t = threadIdx.x, b = blockIdx.x;
  const int l = t & 63, w = t >> 6;
  const int hd = l >> 4;
  const int t0 = b * BKT;

  const float4 z4 = make_float4(0.f, 0.f, 0.f, 0.f);
  #pragma unroll
  for (int i = 0; i < 8; ++i) *(float4*)(acc + (i * 256 + t) * 4) = z4;
  if (t < BKT) {
    *(float4*)(dacc + t * 4) = z4;
    float4 ev = z4;
    if (t0 + t < N) ev = er4[t0 + t];
    *(float4*)(erl + t * 4) = ev;
  }
  __syncthreads();

  const float M = gmaxM[0];
  const int base = bucketBase[b];
  const int end = bucketBase[b + 1];
  float* sPw = sP + w * 256;

  for (int c = base + w * 64; c < end; c += 256) {
    const int cnt = min(64, end - c);
    unsigned int pk = 0;
    float4 pv = z4;
    if (l < cnt) {
      pk = binned[c + l];
      const int s = (int)(pk >> 7);
      const int lt = (int)(pk & 127u);
      const float4 a = el4[s];
      pv.x = __expf(leaky(a.x + erl[lt * 4 + 0]) - M);
      pv.y = __expf(leaky(a.y + erl[lt * 4 + 1]) - M);
      pv.z = __expf(leaky(a.z + erl[lt * 4 + 2]) - M);
      pv.w = __expf(leaky(a.w + erl[lt * 4 + 3]) - M);
    }
    *(float4*)(sPw + l * 4) = pv;

    for (int j = 0; j < cnt; ++j) {
      const unsigned int pj = __shfl(pk, j, 64);
      const int s = (int)(pj >> 7);
      const int lt = (int)(pj & 127u);
      const float p = sPw[j * 4 + hd];
      const float v = bf2f(hbf[(size_t)s * 64 + l]) * p;
      atomicAdd(&acc[lt * 64 + l], v);
      if ((l & 15) == 0) atomicAdd(&dacc[lt * 4 + hd], p);
    }
  }
  __syncthreads();

  // epilogue: 16 rows per iter; lanes 0-15 = one row's 64 cols (float4 each)
  #pragma unroll
  for (int r0 = 0; r0 < BKT; r0 += 16) {
    const int row = r0 + (t >> 4);
    const int gn = t0 + row;
    const int cg = t & 15;
    if (gn < N) {
      const float4 a4 = *(const float4*)(acc + row * 64 + cg * 4);
      const float d = dacc[row * 4 + (cg >> 2)] + 1e-16f;
      float4 o;
      o.x = a4.x / d; o.y = a4.y / d; o.z = a4.z / d; o.w = a4.w / d;
      *(float4*)(&out[(size_t)gn * 64 + cg * 4]) = o;
    }
  }
}

// ---------------------------------------------------------------------------
extern "C" void kernel_launch(void* const* d_in, const int* in_sizes, int n_in,
                              void* d_out, int out_size, void* d_ws, size_t ws_size,
                              hipStream_t stream) {
  const float* feat  = (const float*)d_in[0];
  const float* W     = (const float*)d_in[1];
  const float* attnl = (const float*)d_in[2];
  const float* attnr = (const float*)d_in[3];
  const int* src = (const int*)d_in[4];
  const int* trg = (const int*)d_in[5];
  float* out = (float*)d_out;

  const int N = in_sizes[0] / 128;  // 100000
  const int E = in_sizes[4];        // 1600000

  const int nbL  = (N + 63) / 64;        // 1563 linear blocks
  const int nbkt = (N + BKT - 1) / BKT;  // 782 buckets
  const int nb3  = (E + EPB - 1) / EPB;  // 200 sort blocks

  char* p = (char*)d_ws;
  auto take = [&](size_t bytes) -> char* {
    char* r = p;
    p += (bytes + 255) & ~(size_t)255;
    return r;
  };
  ushort_t* h_bf  = (ushort_t*)take((size_t)N * 64 * 2); // 12.8 MB
  float* el       = (float*)take((size_t)N * 16);        // 1.6 MB
  float* er       = (float*)take((size_t)N * 16);        // 1.6 MB
  unsigned int* binned = (unsigned int*)take((size_t)E * 4); // 6.4 MB
  ushort_t* wfrag = (ushort_t*)take(5 * 4 * 64 * 8 * 2); // 20.5 KB
  int* blockHist  = (int*)take((size_t)nb3 * nbkt * 4);  // 626 KB
  int* colTotal   = (int*)take((size_t)nbkt * 4);
  int* bucketBase = (int*)take((size_t)(nbkt + 1) * 4);
  float* blockmax2 = (float*)take((size_t)nbL * 2 * 4);
  float* gmaxM    = (float*)take(256);

  packw_hist<<<nb3 + 1, 256, 0, stream>>>(W, attnl, attnr, wfrag,
                                          trg, E, nbkt, blockHist, nb3);
  gat_linear<<<nbL, 256, 0, stream>>>(feat, wfrag, h_bf, el, er,
                                      blockmax2, N);
  bucket_scan<<<nbkt, 64, 0, stream>>>(blockHist, nb3, nbkt, colTotal);
  bucket_base<<<1, 256, 0, stream>>>(colTotal, nbkt, bucketBase,
                                     blockmax2, nbL, gmaxM);
  bucket_scatter<<<nb3, 256, 0, stream>>>(src, trg, E, nbkt, blockHist,
                                          bucketBase, binned);
  gat_fusedagg<<<nbkt, 256, 0, stream>>>(binned, bucketBase,
                                         (const float4*)el, (const float4*)er,
                                         h_bf, gmaxM, out, N);
}